// Round 10
// baseline (1082.785 us; speedup 1.0000x reference)
//
#include <hip/hip_runtime.h>
#include <hip/hip_bf16.h>
#include <math.h>

// ---------------------------------------------------------------------------
// Problem constants
// ---------------------------------------------------------------------------
namespace {
constexpr int BROWS = 8192;
constexpr int NLAB  = 4096;
constexpr int NUNL  = 4096;
constexpr int CREAL = 100;
constexpr int CPAD  = 112;    // 7 mfma col-tiles of 16
constexpr int DIM   = 512;
constexpr int MAXIT = 30;

constexpr size_t MiB = 1ull << 20;
// ws layout (bytes).  Peak live ~104.1 MiB; budget proven ~138 MiB.
constexpr size_t OFF_S    = 0;              // ushort[4096][8192] raw S  64 MiB (dead after it0)
constexpr size_t OFF_AU   = 64 * MiB;       // ushort[4096][4096] thresholded A (unlabeled K) 32 MiB
constexpr size_t OFF_EB   = 96 * MiB;       // ushort[8192][512] emb bf16 (dead after simM) 8 MiB
// overlay of EB after simM:
constexpr size_t OFF_XT0  = 96 * MiB;       // ushort[112][8192] X^T ping 1.75 MiB
constexpr size_t OFF_XT1  = 98 * MiB;       // X^T pong
constexpr size_t OFF_XU   = 100 * MiB;      // float[4096][112] exact X (unlabeled)
constexpr size_t OFF_PL   = 102 * MiB;      // float[4096][112] P_lab (static after it0)
// tail (never overlaid):
constexpr size_t OFF_HIST = 104 * MiB;          // float[4096]
constexpr size_t OFF_ERR  = 104 * MiB + 16384;  // float[32]
constexpr size_t OFF_MS   = 104 * MiB + 16768;  // double
constexpr size_t OFF_RN   = 104 * MiB + 32768;  // float[8192]
constexpr size_t MEMSET_LEN = 20480;            // HIST..MS inclusive
}

typedef __attribute__((ext_vector_type(8))) short short8;
typedef __attribute__((ext_vector_type(4))) float floatx4;

__device__ inline ushort f2bf(float f) {
  __hip_bfloat16 h = __float2bfloat16(f);
  union { __hip_bfloat16 b; ushort u; } c; c.b = h; return c.u;
}
__device__ inline float bf2f(ushort u) {
  union { ushort u; __hip_bfloat16 b; } c; c.u = u;
  return __bfloat162float(c.b);
}

// ---------------------------------------------------------------------------
// Fused: row 1/norm + emb fp32 -> bf16 cast.  One block per row, 64 lanes.
// ---------------------------------------------------------------------------
__global__ __launch_bounds__(64) void k_prep(const float* __restrict__ emb,
                                             ushort* __restrict__ Eb,
                                             float* __restrict__ rn) {
  int row = blockIdx.x, l = threadIdx.x;
  const float4* e4 = (const float4*)(emb + (size_t)row * DIM);
  float4 a = e4[2 * l], b = e4[2 * l + 1];
  float f[8] = {a.x, a.y, a.z, a.w, b.x, b.y, b.z, b.w};
  float s = 0.f;
#pragma unroll
  for (int q = 0; q < 8; q++) s += f[q] * f[q];
#pragma unroll
  for (int m = 1; m < 64; m <<= 1) s += __shfl_xor(s, m);
  if (l == 0) rn[row] = 1.0f / fmaxf(sqrtf(s), 1e-12f);
  union { short8 v; ushort u[8]; } o;
#pragma unroll
  for (int q = 0; q < 8; q++) o.u[q] = f2bf(f[q]);
  *(short8*)(Eb + (size_t)row * DIM + l * 8) = o.v;
}

// ---------------------------------------------------------------------------
// X init: bf16 X^T in both ping-pong buffers + exact fp32 unlabeled X
// ---------------------------------------------------------------------------
__global__ __launch_bounds__(256) void k_initX(ushort* __restrict__ X0,
                                               ushort* __restrict__ X1,
                                               float* __restrict__ Xu,
                                               const int* __restrict__ labels) {
  int j = blockIdx.x * 256 + threadIdx.x;       // 0..8191
  int c = blockIdx.y;                            // 0..111
  float v;
  if (j < NLAB) v = (labels[j] == c) ? 1.0f : 0.0f;
  else          v = (c < CREAL) ? 0.01f : 0.0f;
  ushort b = f2bf(v);
  X0[(size_t)c * BROWS + j] = b;
  X1[(size_t)c * BROWS + j] = b;
  if (j >= NLAB) Xu[(size_t)(j - NLAB) * CPAD + c] = (c < CREAL) ? 0.01f : 0.0f;
}

// ---------------------------------------------------------------------------
// MLP 512->256->128->64->1 (verified)
// ---------------------------------------------------------------------------
__global__ __launch_bounds__(256) void k_mlp(const float* __restrict__ emb,
                                             const float* __restrict__ W1, const float* __restrict__ b1,
                                             const float* __restrict__ W2, const float* __restrict__ b2,
                                             const float* __restrict__ W3, const float* __restrict__ b3,
                                             const float* __restrict__ Wc, const float* __restrict__ bc,
                                             float* __restrict__ out) {
  __shared__ float xs[4][512];
  __shared__ float h1[4][256];
  __shared__ float h2[4][128];
  __shared__ float h3[4][64];
  int t = threadIdx.x;
  int r0 = blockIdx.x * 4;
  {
    const float4* src = (const float4*)(emb + (size_t)r0 * DIM);
    float4* dst = (float4*)&xs[0][0];
    dst[t] = src[t];
    dst[t + 256] = src[t + 256];
  }
  __syncthreads();
  {
    float a0 = 0.f, a1 = 0.f, a2 = 0.f, a3 = 0.f;
    for (int k = 0; k < 512; k++) {
      float w = W1[k * 256 + t];
      a0 = fmaf(xs[0][k], w, a0);
      a1 = fmaf(xs[1][k], w, a1);
      a2 = fmaf(xs[2][k], w, a2);
      a3 = fmaf(xs[3][k], w, a3);
    }
    float bb = b1[t];
    h1[0][t] = fmaxf(a0 + bb, 0.f);
    h1[1][t] = fmaxf(a1 + bb, 0.f);
    h1[2][t] = fmaxf(a2 + bb, 0.f);
    h1[3][t] = fmaxf(a3 + bb, 0.f);
  }
  __syncthreads();
  {
    int c = t & 127, rb = (t >> 7) * 2;
    float a0 = 0.f, a1 = 0.f;
    for (int k = 0; k < 256; k++) {
      float w = W2[k * 128 + c];
      a0 = fmaf(h1[rb][k], w, a0);
      a1 = fmaf(h1[rb + 1][k], w, a1);
    }
    float bb = b2[c];
    h2[rb][c] = fmaxf(a0 + bb, 0.f);
    h2[rb + 1][c] = fmaxf(a1 + bb, 0.f);
  }
  __syncthreads();
  {
    int c = t & 63, r = t >> 6;
    float a = 0.f;
    for (int k = 0; k < 128; k++) a = fmaf(h2[r][k], W3[k * 64 + c], a);
    h3[r][c] = fmaxf(a + b3[c], 0.f);
  }
  __syncthreads();
  {
    int r = t >> 6, l = t & 63;
    float v = h3[r][l] * Wc[l];
#pragma unroll
    for (int m = 32; m; m >>= 1) v += __shfl_down(v, m);
    if (l == 0) out[r0 + r] = v + bc[0];
  }
}

// ---------------------------------------------------------------------------
// Similarity, single-bf16 MFMA, symmetry-reduced grid, LDS staging
// (r6 version verbatim — proven 93-95 us).
// ---------------------------------------------------------------------------
__global__ __launch_bounds__(256) void k_simM(const ushort* __restrict__ Eb,
                                              const float* __restrict__ rn,
                                              ushort* __restrict__ S,
                                              double* __restrict__ meansum) {
  int x = blockIdx.x, y = blockIdx.y;
  if (x < 32 && y > x) return;
  __shared__ ushort Ei[128 * 40];
  __shared__ ushort Ej[128 * 40];
  __shared__ float redbuf[4];

  int t = threadIdx.x;
  int w = t >> 6, lane = t & 63;
  int m = lane & 15, g = lane >> 4;
  int ib = (w >> 1) * 64, jb = (w & 1) * 64;
  int i0 = x * 128, j0 = y * 128;

  floatx4 acc[4][4];
#pragma unroll
  for (int a = 0; a < 4; a++)
#pragma unroll
    for (int b = 0; b < 4; b++) acc[a][b] = (floatx4)0.0f;

  int lrow = t >> 1, lhalf = (t & 1) * 16;
  for (int kt = 0; kt < DIM; kt += 32) {
    __syncthreads();
    {
      const ushort* gi = Eb + (size_t)(i0 + lrow) * DIM + kt + lhalf;
      const ushort* gj = Eb + (size_t)(j0 + lrow) * DIM + kt + lhalf;
      int o = lrow * 40 + lhalf;
      *(short8*)&Ei[o]     = *(const short8*)gi;
      *(short8*)&Ei[o + 8] = *(const short8*)(gi + 8);
      *(short8*)&Ej[o]     = *(const short8*)gj;
      *(short8*)&Ej[o + 8] = *(const short8*)(gj + 8);
    }
    __syncthreads();

    short8 ah[4], bh[4];
#pragma unroll
    for (int rt = 0; rt < 4; rt++) ah[rt] = *(const short8*)&Ei[(ib + rt * 16 + m) * 40 + g * 8];
#pragma unroll
    for (int ct = 0; ct < 4; ct++) bh[ct] = *(const short8*)&Ej[(jb + ct * 16 + m) * 40 + g * 8];
#pragma unroll
    for (int rt = 0; rt < 4; rt++)
#pragma unroll
      for (int ct = 0; ct < 4; ct++)
        acc[rt][ct] = __builtin_amdgcn_mfma_f32_16x16x32_bf16(ah[rt], bh[ct], acc[rt][ct], 0, 0, 0);
  }

  bool dostore = (x >= 32);
  bool isdiag  = (x == y);
  float weight = (x < 32) ? (isdiag ? 1.0f : 2.0f) : ((y < 32) ? 2.0f : 1.0f);
  float lsum = 0.f;
#pragma unroll
  for (int rt = 0; rt < 4; rt++) {
    int gi0 = i0 + ib + rt * 16 + g * 4;
    float4 rni = *(const float4*)(rn + gi0);
#pragma unroll
    for (int ct = 0; ct < 4; ct++) {
      int gj = j0 + jb + ct * 16 + m;
      float rnj = rn[gj];
#pragma unroll
      for (int r = 0; r < 4; r++) {
        int gi = gi0 + r;
        float rv = (r == 0) ? rni.x : (r == 1) ? rni.y : (r == 2) ? rni.z : rni.w;
        float s = acc[rt][ct][r] * rv * rnj;
        if (isdiag && gi == gj) s = 0.f;
        s = fminf(fmaxf(s, 0.f), 1.f);
        lsum += s;
        if (dostore) S[(size_t)(gi - NLAB) * BROWS + gj] = f2bf(s);
      }
    }
  }
  lsum *= weight;
#pragma unroll
  for (int d = 1; d < 64; d <<= 1) lsum += __shfl_xor(lsum, d);
  if (lane == 0) redbuf[w] = lsum;
  __syncthreads();
  if (t == 0) atomicAdd(meansum, (double)(redbuf[0] + redbuf[1] + redbuf[2] + redbuf[3]));
}

// ---------------------------------------------------------------------------
// One replicator iteration.  128 blocks x 1024 thr; block owns 32 rows
// (2 row-tiles), 16 waves = 2 rt x 8 kh k-splits.  Halves the X^T L2
// traffic invariant (#blocks x 0.917 MiB): 235 -> 117 MB/iter.
// Two-phase LDS reduction (rt=0 partials, then rt=1 through the same 8
// buffers); P buffer aliases the partial buffer after a sync.
// it==0: full K=8192 (kh*1024), threshold in regs, persist unlabeled half
// (kh>=4) to Au, labeled partial (kh 0-3) saved as Plab.
// Convergence: skip iff errsq[it-1] <= TOL^2 (skip chains = reference loop).
// ---------------------------------------------------------------------------
__global__ __launch_bounds__(1024, 4) void k_iter(const ushort* __restrict__ S,
                                                  ushort* __restrict__ Au,
                                                  const ushort* __restrict__ XTr,
                                                  ushort* __restrict__ XTw,
                                                  float* __restrict__ Xu,
                                                  float* __restrict__ Plab,
                                                  float* __restrict__ hist,
                                                  float* __restrict__ errsq,
                                                  const double* __restrict__ ms,
                                                  int it) {
  if (it > 0 && errsq[it - 1] <= 1e-6f) return;
  __shared__ float part[8][16 * 113];   // 57856 B; reused as P buffer (stride 114)
  __shared__ float dsqbuf[16];
  float* Pflat = &part[0][0];
  int t = threadIdx.x;
  int w = t >> 6, lane = t & 63;
  int m = lane & 15, g = lane >> 4;
  int r0 = blockIdx.x * 32;             // unlabeled row base (i' space)
  int rt = w & 1, kh = w >> 1;          // 2 row-tiles x 8 k-splits
  int arow = r0 + rt * 16 + m;

  floatx4 acc[7];
#pragma unroll
  for (int c = 0; c < 7; c++) acc[c] = (floatx4)0.0f;

  if (it == 0) {
    float mean = (float)(ms[0] * (1.0 / ((double)BROWS * (double)BROWS)));
    int kw = kh * 1024;                 // full K 8192 / 8
    size_t so = (size_t)arow * BROWS + kw + g * 8;
    short8 sC = __builtin_nontemporal_load((const short8*)(S + so));
    for (int ks = 0; ks < 32; ks++) {
      short8 sN;
      if (ks < 31) sN = __builtin_nontemporal_load((const short8*)(S + so + (ks + 1) * 32));
      union { short8 v; ushort u[8]; } ua; ua.v = sC;
#pragma unroll
      for (int e = 0; e < 8; e++) {
        float s = bf2f(ua.u[e]);
        float av = (s < mean) ? 1.0f : 1.0f - s;
        ua.u[e] = f2bf(av);
      }
      short8 a = ua.v;
      if (kh >= 4)   // unlabeled K half -> persist for it>0
        *(short8*)(Au + (size_t)arow * NUNL + (kw - NLAB) + ks * 32 + g * 8) = a;
#pragma unroll
      for (int ct = 0; ct < 7; ct++) {
        short8 b = *(const short8*)(XTr + (size_t)(ct * 16 + m) * BROWS + kw + ks * 32 + g * 8);
        acc[ct] = __builtin_amdgcn_mfma_f32_16x16x32_bf16(a, b, acc[ct], 0, 0, 0);
      }
      sC = sN;
    }
  } else {
    int kw = kh * 512;                  // Au-relative K 4096 / 8
    size_t ab = (size_t)arow * NUNL + kw + g * 8;
    size_t bb = (size_t)m * BROWS + NLAB + kw + g * 8;
    for (int ks = 0; ks < 16; ks++) {
      short8 a = __builtin_nontemporal_load((const short8*)(Au + ab + ks * 32));
#pragma unroll
      for (int ct = 0; ct < 7; ct++) {
        short8 b = *(const short8*)(XTr + bb + (size_t)ct * 16 * BROWS + ks * 32);
        acc[ct] = __builtin_amdgcn_mfma_f32_16x16x32_bf16(a, b, acc[ct], 0, 0, 0);
      }
    }
  }

  // ---- two-phase reduction over kh through 8 LDS buffers ----
  // (D-frag map: row = g*4+r, col = ct*16+m)
  float pA0[2], pA1[2], pB0[2], pB1[2];
  if (rt == 0) {
#pragma unroll
    for (int ct = 0; ct < 7; ct++)
#pragma unroll
      for (int r = 0; r < 4; r++)
        part[kh][(g * 4 + r) * 113 + ct * 16 + m] = acc[ct][r];
  }
  __syncthreads();
#pragma unroll
  for (int q = 0; q < 2; q++) {
    int idx = t + q * 1024;
    pA0[q] = pA1[q] = 0.f;
    if (idx < 16 * CPAD) {
      int o = (idx / CPAD) * 113 + (idx % CPAD);
      pA0[q] = (part[0][o] + part[1][o]) + (part[2][o] + part[3][o]);   // kh 0-3 (labeled at it0)
      pA1[q] = (part[4][o] + part[5][o]) + (part[6][o] + part[7][o]);   // kh 4-7
    }
  }
  __syncthreads();
  if (rt == 1) {
#pragma unroll
    for (int ct = 0; ct < 7; ct++)
#pragma unroll
      for (int r = 0; r < 4; r++)
        part[kh][(g * 4 + r) * 113 + ct * 16 + m] = acc[ct][r];
  }
  __syncthreads();
#pragma unroll
  for (int q = 0; q < 2; q++) {
    int idx = t + q * 1024;
    pB0[q] = pB1[q] = 0.f;
    if (idx < 16 * CPAD) {
      int o = (idx / CPAD) * 113 + (idx % CPAD);
      pB0[q] = (part[0][o] + part[1][o]) + (part[2][o] + part[3][o]);
      pB1[q] = (part[4][o] + part[5][o]) + (part[6][o] + part[7][o]);
    }
  }
  __syncthreads();                      // all partial reads done before P overwrite

  // ---- P assembly (+Plab store/add), written into the aliased LDS buffer ----
#pragma unroll
  for (int q = 0; q < 2; q++) {
    int idx = t + q * 1024;
    if (idx < 16 * CPAD) {
      int row = idx / CPAD, col = idx % CPAD;
      size_t goA = (size_t)(r0 + row) * CPAD + col;
      size_t goB = (size_t)(r0 + 16 + row) * CPAD + col;
      float PA, PB;
      if (it == 0) {
        Plab[goA] = pA0[q]; PA = pA0[q] + pA1[q];
        Plab[goB] = pB0[q]; PB = pB0[q] + pB1[q];
      } else {
        PA = pA0[q] + pA1[q] + Plab[goA];
        PB = pB0[q] + pB1[q] + Plab[goB];
      }
      Pflat[row * 114 + col] = PA;
      Pflat[(16 + row) * 114 + col] = PB;
    }
  }
  __syncthreads();

  // ---- fused epilogue: wave w handles rows w*2, w*2+1 ----
  float dsq_acc = 0.f;
  bool act = lane < 56;
#pragma unroll
  for (int rr = 0; rr < 2; rr++) {
    int row = w * 2 + rr;
    int gr = r0 + row;
    float2 p = make_float2(0.f, 0.f), xo = make_float2(0.f, 0.f);
    if (act) {
      p = *(const float2*)&Pflat[row * 114 + lane * 2];
      xo = *(const float2*)(Xu + (size_t)gr * CPAD + lane * 2);
    }
    float2 xn;
    xn.x = xo.x * p.x;
    xn.y = xo.y * p.y;
    float s = xn.x + xn.y;
#pragma unroll
    for (int d = 1; d < 64; d <<= 1) s += __shfl_xor(s, d);
    float inv = 1.0f / s;
    float ent = 0.f, dsq = 0.f;
    if (act) {
      xn.x *= inv; xn.y *= inv;
      ent = -(xn.x * log2f(xn.x + 1e-20f) + xn.y * log2f(xn.y + 1e-20f));
      float dx = xn.x - xo.x, dy = xn.y - xo.y;
      dsq = dx * dx + dy * dy;
      *(float2*)(Xu + (size_t)gr * CPAD + lane * 2) = xn;
      int c0 = lane * 2, jg = NLAB + gr;
      XTw[(size_t)c0 * BROWS + jg]       = f2bf(xn.x);
      XTw[(size_t)(c0 + 1) * BROWS + jg] = f2bf(xn.y);
    }
#pragma unroll
    for (int d = 1; d < 64; d <<= 1) { ent += __shfl_xor(ent, d); dsq += __shfl_xor(dsq, d); }
    if (lane == 0) {
      hist[gr] += ent;
      dsq_acc += dsq;
    }
  }
  if (lane == 0) dsqbuf[w] = dsq_acc;
  __syncthreads();
  if (t == 0) {
    float ds = 0.f;
#pragma unroll
    for (int i = 0; i < 16; i++) ds += dsqbuf[i];
    atomicAdd(&errsq[it], ds);
  }
}

__global__ __launch_bounds__(256) void k_final(const float* __restrict__ hist,
                                               float* __restrict__ out) {
  int i = blockIdx.x * 256 + threadIdx.x;
  float yt = (i < NLAB) ? 0.0f : hist[i - NLAB] * (1.0f / 30.0f);
  out[BROWS + i] = yt;
  out[2 * BROWS + i] = (i < NLAB) ? 1.0f : 0.0f;
}

// ---------------------------------------------------------------------------
extern "C" void kernel_launch(void* const* d_in, const int* in_sizes, int n_in,
                              void* d_out, int out_size, void* d_ws, size_t ws_size,
                              hipStream_t stream) {
  const float* emb    = (const float*)d_in[1];
  const int*   labels = (const int*)d_in[2];
  const float* W1 = (const float*)d_in[3];
  const float* b1 = (const float*)d_in[4];
  const float* W2 = (const float*)d_in[5];
  const float* b2 = (const float*)d_in[6];
  const float* W3 = (const float*)d_in[7];
  const float* b3 = (const float*)d_in[8];
  const float* Wc = (const float*)d_in[9];
  const float* bc = (const float*)d_in[10];
  float* out = (float*)d_out;

  char* ws = (char*)d_ws;
  ushort* S    = (ushort*)(ws + OFF_S);
  ushort* Au   = (ushort*)(ws + OFF_AU);
  ushort* Eb   = (ushort*)(ws + OFF_EB);
  ushort* XT0  = (ushort*)(ws + OFF_XT0);
  ushort* XT1  = (ushort*)(ws + OFF_XT1);
  float*  Xu   = (float*)(ws + OFF_XU);
  float*  Plab = (float*)(ws + OFF_PL);
  float*  hist = (float*)(ws + OFF_HIST);
  float*  errs = (float*)(ws + OFF_ERR);
  double* ms   = (double*)(ws + OFF_MS);
  float*  rn   = (float*)(ws + OFF_RN);

  // zero hist + errsq + mean accumulator
  hipMemsetAsync(ws + OFF_HIST, 0, MEMSET_LEN, stream);

  k_prep<<<BROWS, 64, 0, stream>>>(emb, Eb, rn);
  k_mlp<<<BROWS / 4, 256, 0, stream>>>(emb, W1, b1, W2, b2, W3, b3, Wc, bc, out);

  { dim3 g(BROWS / 128, BROWS / 128); k_simM<<<g, 256, 0, stream>>>(Eb, rn, S, ms); }

  // overlay init (Eb dead now)
  { dim3 g(BROWS / 256, CPAD); k_initX<<<g, 256, 0, stream>>>(XT0, XT1, Xu, labels); }

  for (int it = 0; it < MAXIT; it++) {
    const ushort* XTr = (it & 1) ? XT1 : XT0;
    ushort*       XTw = (it & 1) ? XT0 : XT1;
    k_iter<<<NUNL / 32, 1024, 0, stream>>>(S, Au, XTr, XTw, Xu, Plab, hist, errs, ms, it);
  }

  k_final<<<BROWS / 256, 256, 0, stream>>>(hist, out);
}

// Round 11
// 725.798 us; speedup vs baseline: 1.4919x; 1.4919x over previous
//
#include <hip/hip_runtime.h>
#include <hip/hip_bf16.h>
#include <math.h>

// ---------------------------------------------------------------------------
// Problem constants
// ---------------------------------------------------------------------------
namespace {
constexpr int BROWS = 8192;
constexpr int NLAB  = 4096;
constexpr int NUNL  = 4096;
constexpr int CREAL = 100;
constexpr int CPAD  = 112;    // 7 mfma col-tiles of 16
constexpr int DIM   = 512;
constexpr int MAXIT = 30;

constexpr size_t MiB = 1ull << 20;
// ws layout (bytes).  Peak live ~104.1 MiB; budget proven ~138 MiB.
constexpr size_t OFF_S    = 0;              // ushort[4096][8192] raw S  64 MiB (dead after it0)
constexpr size_t OFF_AU   = 64 * MiB;       // ushort[4096][4096] thresholded A (unlabeled K) 32 MiB
constexpr size_t OFF_EB   = 96 * MiB;       // ushort[8192][512] emb bf16 (dead after simM) 8 MiB
// overlay of EB after simM:
constexpr size_t OFF_XT0  = 96 * MiB;       // ushort[112][8192] X^T ping 1.75 MiB
constexpr size_t OFF_XT1  = 98 * MiB;       // X^T pong
constexpr size_t OFF_XU   = 100 * MiB;      // float[4096][112] exact X (unlabeled)
constexpr size_t OFF_PL   = 102 * MiB;      // float[4096][112] P_lab (static after it0)
// tail (never overlaid):
constexpr size_t OFF_HIST = 104 * MiB;          // float[4096]
constexpr size_t OFF_ERR  = 104 * MiB + 16384;  // float[32]
constexpr size_t OFF_MS   = 104 * MiB + 16768;  // double
constexpr size_t OFF_RN   = 104 * MiB + 32768;  // float[8192]
constexpr size_t MEMSET_LEN = 20480;            // HIST..MS inclusive
}

typedef __attribute__((ext_vector_type(8))) short short8;
typedef __attribute__((ext_vector_type(4))) float floatx4;

__device__ inline ushort f2bf(float f) {
  __hip_bfloat16 h = __float2bfloat16(f);
  union { __hip_bfloat16 b; ushort u; } c; c.b = h; return c.u;
}
__device__ inline float bf2f(ushort u) {
  union { ushort u; __hip_bfloat16 b; } c; c.u = u;
  return __bfloat162float(c.b);
}

// ---------------------------------------------------------------------------
// Fused: row 1/norm + emb fp32 -> bf16 cast.  One block per row, 64 lanes.
// ---------------------------------------------------------------------------
__global__ __launch_bounds__(64) void k_prep(const float* __restrict__ emb,
                                             ushort* __restrict__ Eb,
                                             float* __restrict__ rn) {
  int row = blockIdx.x, l = threadIdx.x;
  const float4* e4 = (const float4*)(emb + (size_t)row * DIM);
  float4 a = e4[2 * l], b = e4[2 * l + 1];
  float f[8] = {a.x, a.y, a.z, a.w, b.x, b.y, b.z, b.w};
  float s = 0.f;
#pragma unroll
  for (int q = 0; q < 8; q++) s += f[q] * f[q];
#pragma unroll
  for (int m = 1; m < 64; m <<= 1) s += __shfl_xor(s, m);
  if (l == 0) rn[row] = 1.0f / fmaxf(sqrtf(s), 1e-12f);
  union { short8 v; ushort u[8]; } o;
#pragma unroll
  for (int q = 0; q < 8; q++) o.u[q] = f2bf(f[q]);
  *(short8*)(Eb + (size_t)row * DIM + l * 8) = o.v;
}

// ---------------------------------------------------------------------------
// X init: bf16 X^T in both ping-pong buffers + exact fp32 unlabeled X
// ---------------------------------------------------------------------------
__global__ __launch_bounds__(256) void k_initX(ushort* __restrict__ X0,
                                               ushort* __restrict__ X1,
                                               float* __restrict__ Xu,
                                               const int* __restrict__ labels) {
  int j = blockIdx.x * 256 + threadIdx.x;       // 0..8191
  int c = blockIdx.y;                            // 0..111
  float v;
  if (j < NLAB) v = (labels[j] == c) ? 1.0f : 0.0f;
  else          v = (c < CREAL) ? 0.01f : 0.0f;
  ushort b = f2bf(v);
  X0[(size_t)c * BROWS + j] = b;
  X1[(size_t)c * BROWS + j] = b;
  if (j >= NLAB) Xu[(size_t)(j - NLAB) * CPAD + c] = (c < CREAL) ? 0.01f : 0.0f;
}

// ---------------------------------------------------------------------------
// MLP 512->256->128->64->1 (verified)
// ---------------------------------------------------------------------------
__global__ __launch_bounds__(256) void k_mlp(const float* __restrict__ emb,
                                             const float* __restrict__ W1, const float* __restrict__ b1,
                                             const float* __restrict__ W2, const float* __restrict__ b2,
                                             const float* __restrict__ W3, const float* __restrict__ b3,
                                             const float* __restrict__ Wc, const float* __restrict__ bc,
                                             float* __restrict__ out) {
  __shared__ float xs[4][512];
  __shared__ float h1[4][256];
  __shared__ float h2[4][128];
  __shared__ float h3[4][64];
  int t = threadIdx.x;
  int r0 = blockIdx.x * 4;
  {
    const float4* src = (const float4*)(emb + (size_t)r0 * DIM);
    float4* dst = (float4*)&xs[0][0];
    dst[t] = src[t];
    dst[t + 256] = src[t + 256];
  }
  __syncthreads();
  {
    float a0 = 0.f, a1 = 0.f, a2 = 0.f, a3 = 0.f;
    for (int k = 0; k < 512; k++) {
      float w = W1[k * 256 + t];
      a0 = fmaf(xs[0][k], w, a0);
      a1 = fmaf(xs[1][k], w, a1);
      a2 = fmaf(xs[2][k], w, a2);
      a3 = fmaf(xs[3][k], w, a3);
    }
    float bb = b1[t];
    h1[0][t] = fmaxf(a0 + bb, 0.f);
    h1[1][t] = fmaxf(a1 + bb, 0.f);
    h1[2][t] = fmaxf(a2 + bb, 0.f);
    h1[3][t] = fmaxf(a3 + bb, 0.f);
  }
  __syncthreads();
  {
    int c = t & 127, rb = (t >> 7) * 2;
    float a0 = 0.f, a1 = 0.f;
    for (int k = 0; k < 256; k++) {
      float w = W2[k * 128 + c];
      a0 = fmaf(h1[rb][k], w, a0);
      a1 = fmaf(h1[rb + 1][k], w, a1);
    }
    float bb = b2[c];
    h2[rb][c] = fmaxf(a0 + bb, 0.f);
    h2[rb + 1][c] = fmaxf(a1 + bb, 0.f);
  }
  __syncthreads();
  {
    int c = t & 63, r = t >> 6;
    float a = 0.f;
    for (int k = 0; k < 128; k++) a = fmaf(h2[r][k], W3[k * 64 + c], a);
    h3[r][c] = fmaxf(a + b3[c], 0.f);
  }
  __syncthreads();
  {
    int r = t >> 6, l = t & 63;
    float v = h3[r][l] * Wc[l];
#pragma unroll
    for (int m = 32; m; m >>= 1) v += __shfl_down(v, m);
    if (l == 0) out[r0 + r] = v + bc[0];
  }
}

// ---------------------------------------------------------------------------
// Similarity, single-bf16 MFMA, symmetry-reduced grid.  DOUBLE-BUFFERED LDS
// staging: chunk kt+1 prefetched to registers during MFMA on chunk kt, one
// barrier per chunk (16 vs 32), global loads overlap MFMA.
// ---------------------------------------------------------------------------
__global__ __launch_bounds__(256) void k_simM(const ushort* __restrict__ Eb,
                                              const float* __restrict__ rn,
                                              ushort* __restrict__ S,
                                              double* __restrict__ meansum) {
  int x = blockIdx.x, y = blockIdx.y;
  if (x < 32 && y > x) return;
  __shared__ ushort Ei[2][128 * 40];
  __shared__ ushort Ej[2][128 * 40];
  __shared__ float redbuf[4];

  int t = threadIdx.x;
  int w = t >> 6, lane = t & 63;
  int m = lane & 15, g = lane >> 4;
  int ib = (w >> 1) * 64, jb = (w & 1) * 64;
  int i0 = x * 128, j0 = y * 128;

  floatx4 acc[4][4];
#pragma unroll
  for (int a = 0; a < 4; a++)
#pragma unroll
    for (int b = 0; b < 4; b++) acc[a][b] = (floatx4)0.0f;

  int lrow = t >> 1, lhalf = (t & 1) * 16;
  const ushort* gib = Eb + (size_t)(i0 + lrow) * DIM + lhalf;
  const ushort* gjb = Eb + (size_t)(j0 + lrow) * DIM + lhalf;
  int o = lrow * 40 + lhalf;

  // stage chunk 0
  short8 ri0 = *(const short8*)gib;
  short8 ri1 = *(const short8*)(gib + 8);
  short8 rj0 = *(const short8*)gjb;
  short8 rj1 = *(const short8*)(gjb + 8);
  *(short8*)&Ei[0][o] = ri0; *(short8*)&Ei[0][o + 8] = ri1;
  *(short8*)&Ej[0][o] = rj0; *(short8*)&Ej[0][o + 8] = rj1;
  __syncthreads();

  for (int c = 0; c < 16; c++) {
    int p = c & 1;
    if (c < 15) {                        // prefetch chunk c+1 to registers
      int kt = (c + 1) * 32;
      ri0 = *(const short8*)(gib + kt);
      ri1 = *(const short8*)(gib + kt + 8);
      rj0 = *(const short8*)(gjb + kt);
      rj1 = *(const short8*)(gjb + kt + 8);
    }
    short8 ah[4], bh[4];
#pragma unroll
    for (int rt = 0; rt < 4; rt++) ah[rt] = *(const short8*)&Ei[p][(ib + rt * 16 + m) * 40 + g * 8];
#pragma unroll
    for (int ct = 0; ct < 4; ct++) bh[ct] = *(const short8*)&Ej[p][(jb + ct * 16 + m) * 40 + g * 8];
#pragma unroll
    for (int rt = 0; rt < 4; rt++)
#pragma unroll
      for (int ct = 0; ct < 4; ct++)
        acc[rt][ct] = __builtin_amdgcn_mfma_f32_16x16x32_bf16(ah[rt], bh[ct], acc[rt][ct], 0, 0, 0);
    if (c < 15) {                        // write prefetched chunk to alternate buffer
      *(short8*)&Ei[p ^ 1][o] = ri0; *(short8*)&Ei[p ^ 1][o + 8] = ri1;
      *(short8*)&Ej[p ^ 1][o] = rj0; *(short8*)&Ej[p ^ 1][o + 8] = rj1;
    }
    __syncthreads();
  }

  bool dostore = (x >= 32);
  bool isdiag  = (x == y);
  float weight = (x < 32) ? (isdiag ? 1.0f : 2.0f) : ((y < 32) ? 2.0f : 1.0f);
  float lsum = 0.f;
#pragma unroll
  for (int rt = 0; rt < 4; rt++) {
    int gi0 = i0 + ib + rt * 16 + g * 4;
    float4 rni = *(const float4*)(rn + gi0);
#pragma unroll
    for (int ct = 0; ct < 4; ct++) {
      int gj = j0 + jb + ct * 16 + m;
      float rnj = rn[gj];
#pragma unroll
      for (int r = 0; r < 4; r++) {
        int gi = gi0 + r;
        float rv = (r == 0) ? rni.x : (r == 1) ? rni.y : (r == 2) ? rni.z : rni.w;
        float s = acc[rt][ct][r] * rv * rnj;
        if (isdiag && gi == gj) s = 0.f;
        s = fminf(fmaxf(s, 0.f), 1.f);
        lsum += s;
        if (dostore) S[(size_t)(gi - NLAB) * BROWS + gj] = f2bf(s);
      }
    }
  }
  lsum *= weight;
#pragma unroll
  for (int d = 1; d < 64; d <<= 1) lsum += __shfl_xor(lsum, d);
  if (lane == 0) redbuf[w] = lsum;
  __syncthreads();
  if (t == 0) atomicAdd(meansum, (double)(redbuf[0] + redbuf[1] + redbuf[2] + redbuf[3]));
}

// ---------------------------------------------------------------------------
// One replicator iteration (r6 structure, 256 blocks x 1024 thr, proven).
// PLAIN (non-NT) loads for S and Au: both are LLC-resident (S written by
// simM, Au persists across 29 iters) — NT was forcing HBM re-reads.
// Convergence: skip iff errsq[it-1] <= TOL^2 (skip chains = reference loop).
// ---------------------------------------------------------------------------
__global__ __launch_bounds__(1024, 4) void k_iter(const ushort* __restrict__ S,
                                                  ushort* __restrict__ Au,
                                                  const ushort* __restrict__ XTr,
                                                  ushort* __restrict__ XTw,
                                                  float* __restrict__ Xu,
                                                  float* __restrict__ Plab,
                                                  float* __restrict__ hist,
                                                  float* __restrict__ errsq,
                                                  const double* __restrict__ ms,
                                                  int it) {
  if (it > 0 && errsq[it - 1] <= 1e-6f) return;
  __shared__ float part[8][16 * 113];   // 57856 B
  __shared__ float Pbuf[16 * 114];      //  7296 B
  __shared__ float dsqbuf[16];
  int t = threadIdx.x;
  int w = t >> 6, lane = t & 63;
  int m = lane & 15, g = lane >> 4;
  int r0 = blockIdx.x * 16;             // unlabeled row base (i' space)

  floatx4 acc[7];
#pragma unroll
  for (int c = 0; c < 7; c++) acc[c] = (floatx4)0.0f;

  if (it == 0) {
    float mean = (float)(ms[0] * (1.0 / ((double)BROWS * (double)BROWS)));
    int kw = w * 512;                   // wave w: k in [w*512, w*512+512)
    for (int ks = 0; ks < 16; ks++) {
      int kk = kw + ks * 32;
      size_t so = (size_t)(r0 + m) * BROWS + kk + g * 8;
      short8 a = *(const short8*)(S + so);
      union { short8 v; ushort u[8]; } ua; ua.v = a;
#pragma unroll
      for (int e = 0; e < 8; e++) {
        float s = bf2f(ua.u[e]);
        float av = (s < mean) ? 1.0f : 1.0f - s;
        ua.u[e] = f2bf(av);
      }
      a = ua.v;
      if (w >= 8)   // unlabeled K half -> persist for it>0
        *(short8*)(Au + (size_t)(r0 + m) * NUNL + (kk - NLAB) + g * 8) = a;
#pragma unroll
      for (int ct = 0; ct < 7; ct++) {
        short8 b = *(const short8*)(XTr + (size_t)(ct * 16 + m) * BROWS + kk + g * 8);
        acc[ct] = __builtin_amdgcn_mfma_f32_16x16x32_bf16(a, b, acc[ct], 0, 0, 0);
      }
    }
  } else {
    int kw = w * 256;                   // Au-relative: wave w k in [w*256,+256)
    size_t abase = (size_t)(r0 + m) * NUNL + kw + g * 8;
    size_t bbase = (size_t)m * BROWS + NLAB + kw + g * 8;
    for (int ks = 0; ks < 8; ks++) {
      short8 a = *(const short8*)(Au + abase + ks * 32);
#pragma unroll
      for (int ct = 0; ct < 7; ct++) {
        short8 b = *(const short8*)(XTr + bbase + (size_t)ct * 16 * BROWS + ks * 32);
        acc[ct] = __builtin_amdgcn_mfma_f32_16x16x32_bf16(a, b, acc[ct], 0, 0, 0);
      }
    }
  }

  // ---- two-phase reduction of 16 wave-partials through 8 LDS buffers ----
  // (D-frag map: row = g*4+r, col = ct*16+m)
  if (w < 8) {
#pragma unroll
    for (int ct = 0; ct < 7; ct++)
#pragma unroll
      for (int r = 0; r < 4; r++)
        part[w][(g * 4 + r) * 113 + ct * 16 + m] = acc[ct][r];
  }
  __syncthreads();
  float sA[2] = {0.f, 0.f}, sB[2] = {0.f, 0.f};
#pragma unroll
  for (int q = 0; q < 2; q++) {
    int idx = t + q * 1024;
    if (idx < 16 * CPAD) {
      int row = idx / CPAD, col = idx % CPAD;
      int o = row * 113 + col;
      sA[q] = ((part[0][o] + part[1][o]) + (part[2][o] + part[3][o]))
            + ((part[4][o] + part[5][o]) + (part[6][o] + part[7][o]));
    }
  }
  __syncthreads();
  if (w >= 8) {
#pragma unroll
    for (int ct = 0; ct < 7; ct++)
#pragma unroll
      for (int r = 0; r < 4; r++)
        part[w - 8][(g * 4 + r) * 113 + ct * 16 + m] = acc[ct][r];
  }
  __syncthreads();
#pragma unroll
  for (int q = 0; q < 2; q++) {
    int idx = t + q * 1024;
    if (idx < 16 * CPAD) {
      int row = idx / CPAD, col = idx % CPAD;
      int o = row * 113 + col;
      sB[q] = ((part[0][o] + part[1][o]) + (part[2][o] + part[3][o]))
            + ((part[4][o] + part[5][o]) + (part[6][o] + part[7][o]));
      float P;
      size_t go = (size_t)(r0 + row) * CPAD + col;
      if (it == 0) { Plab[go] = sA[q]; P = sA[q] + sB[q]; }  // waves 0-7 = labeled K
      else         { P = sA[q] + sB[q] + Plab[go]; }
      Pbuf[row * 114 + col] = P;
    }
  }
  __syncthreads();

  // ---- fused epilogue: wave w handles row w ----
  int gr = r0 + w;
  bool act = lane < 56;
  float2 p = make_float2(0.f, 0.f), xo = make_float2(0.f, 0.f);
  if (act) {
    p = *(const float2*)&Pbuf[w * 114 + lane * 2];
    xo = *(const float2*)(Xu + (size_t)gr * CPAD + lane * 2);
  }
  float2 xn;
  xn.x = xo.x * p.x;
  xn.y = xo.y * p.y;
  float s = xn.x + xn.y;
#pragma unroll
  for (int d = 1; d < 64; d <<= 1) s += __shfl_xor(s, d);
  float inv = 1.0f / s;
  float ent = 0.f, dsq = 0.f;
  if (act) {
    xn.x *= inv; xn.y *= inv;
    ent = -(xn.x * log2f(xn.x + 1e-20f) + xn.y * log2f(xn.y + 1e-20f));
    float dx = xn.x - xo.x, dy = xn.y - xo.y;
    dsq = dx * dx + dy * dy;
    *(float2*)(Xu + (size_t)gr * CPAD + lane * 2) = xn;
    int c0 = lane * 2, jg = NLAB + gr;
    XTw[(size_t)c0 * BROWS + jg]       = f2bf(xn.x);
    XTw[(size_t)(c0 + 1) * BROWS + jg] = f2bf(xn.y);
  }
#pragma unroll
  for (int d = 1; d < 64; d <<= 1) { ent += __shfl_xor(ent, d); dsq += __shfl_xor(dsq, d); }
  if (lane == 0) {
    hist[gr] += ent;
    dsqbuf[w] = dsq;
  }
  __syncthreads();
  if (t == 0) {
    float ds = 0.f;
#pragma unroll
    for (int i = 0; i < 16; i++) ds += dsqbuf[i];
    atomicAdd(&errsq[it], ds);
  }
}

__global__ __launch_bounds__(256) void k_final(const float* __restrict__ hist,
                                               float* __restrict__ out) {
  int i = blockIdx.x * 256 + threadIdx.x;
  float yt = (i < NLAB) ? 0.0f : hist[i - NLAB] * (1.0f / 30.0f);
  out[BROWS + i] = yt;
  out[2 * BROWS + i] = (i < NLAB) ? 1.0f : 0.0f;
}

// ---------------------------------------------------------------------------
extern "C" void kernel_launch(void* const* d_in, const int* in_sizes, int n_in,
                              void* d_out, int out_size, void* d_ws, size_t ws_size,
                              hipStream_t stream) {
  const float* emb    = (const float*)d_in[1];
  const int*   labels = (const int*)d_in[2];
  const float* W1 = (const float*)d_in[3];
  const float* b1 = (const float*)d_in[4];
  const float* W2 = (const float*)d_in[5];
  const float* b2 = (const float*)d_in[6];
  const float* W3 = (const float*)d_in[7];
  const float* b3 = (const float*)d_in[8];
  const float* Wc = (const float*)d_in[9];
  const float* bc = (const float*)d_in[10];
  float* out = (float*)d_out;

  char* ws = (char*)d_ws;
  ushort* S    = (ushort*)(ws + OFF_S);
  ushort* Au   = (ushort*)(ws + OFF_AU);
  ushort* Eb   = (ushort*)(ws + OFF_EB);
  ushort* XT0  = (ushort*)(ws + OFF_XT0);
  ushort* XT1  = (ushort*)(ws + OFF_XT1);
  float*  Xu   = (float*)(ws + OFF_XU);
  float*  Plab = (float*)(ws + OFF_PL);
  float*  hist = (float*)(ws + OFF_HIST);
  float*  errs = (float*)(ws + OFF_ERR);
  double* ms   = (double*)(ws + OFF_MS);
  float*  rn   = (float*)(ws + OFF_RN);

  // zero hist + errsq + mean accumulator
  hipMemsetAsync(ws + OFF_HIST, 0, MEMSET_LEN, stream);

  k_prep<<<BROWS, 64, 0, stream>>>(emb, Eb, rn);
  k_mlp<<<BROWS / 4, 256, 0, stream>>>(emb, W1, b1, W2, b2, W3, b3, Wc, bc, out);

  { dim3 g(BROWS / 128, BROWS / 128); k_simM<<<g, 256, 0, stream>>>(Eb, rn, S, ms); }

  // overlay init (Eb dead now)
  { dim3 g(BROWS / 256, CPAD); k_initX<<<g, 256, 0, stream>>>(XT0, XT1, Xu, labels); }

  for (int it = 0; it < MAXIT; it++) {
    const ushort* XTr = (it & 1) ? XT1 : XT0;
    ushort*       XTw = (it & 1) ? XT0 : XT1;
    k_iter<<<NUNL / 16, 1024, 0, stream>>>(S, Au, XTr, XTw, Xu, Plab, hist, errs, ms, it);
  }

  k_final<<<BROWS / 256, 256, 0, stream>>>(hist, out);
}

// Round 12
// 696.843 us; speedup vs baseline: 1.5538x; 1.0416x over previous
//
#include <hip/hip_runtime.h>
#include <hip/hip_bf16.h>
#include <math.h>

// ---------------------------------------------------------------------------
// Problem constants
// ---------------------------------------------------------------------------
namespace {
constexpr int BROWS = 8192;
constexpr int NLAB  = 4096;
constexpr int NUNL  = 4096;
constexpr int CREAL = 100;
constexpr int CPAD  = 112;    // 7 mfma col-tiles of 16
constexpr int DIM   = 512;
constexpr int MAXIT = 30;

constexpr size_t MiB = 1ull << 20;
// ws layout (bytes).  Peak live ~104.1 MiB; budget proven ~138 MiB.
constexpr size_t OFF_S    = 0;              // ushort[4096][8192] raw S  64 MiB (dead after it0)
constexpr size_t OFF_AU   = 64 * MiB;       // ushort[4096][4096] thresholded A (unlabeled K) 32 MiB
constexpr size_t OFF_EB   = 96 * MiB;       // ushort[8192][512] emb bf16 (dead after simM) 8 MiB
// overlay of EB after simM:
constexpr size_t OFF_XT0  = 96 * MiB;       // ushort[112][8192] X^T ping 1.75 MiB
constexpr size_t OFF_XT1  = 98 * MiB;       // X^T pong
constexpr size_t OFF_XU   = 100 * MiB;      // float[4096][112] exact X (unlabeled)
constexpr size_t OFF_PL   = 102 * MiB;      // float[4096][112] P_lab (static after it0)
// tail (never overlaid):
constexpr size_t OFF_HIST = 104 * MiB;          // float[4096]
constexpr size_t OFF_ERR  = 104 * MiB + 16384;  // float[32]
constexpr size_t OFF_MS   = 104 * MiB + 16768;  // double
constexpr size_t OFF_RN   = 104 * MiB + 32768;  // float[8192]
constexpr size_t MEMSET_LEN = 20480;            // HIST..MS inclusive
}

typedef __attribute__((ext_vector_type(8))) short short8;
typedef __attribute__((ext_vector_type(4))) float floatx4;

__device__ inline ushort f2bf(float f) {
  __hip_bfloat16 h = __float2bfloat16(f);
  union { __hip_bfloat16 b; ushort u; } c; c.b = h; return c.u;
}
__device__ inline float bf2f(ushort u) {
  union { ushort u; __hip_bfloat16 b; } c; c.u = u;
  return __bfloat162float(c.b);
}

// ---------------------------------------------------------------------------
// Fused: row 1/norm + emb fp32 -> bf16 cast.  One block per row, 64 lanes.
// ---------------------------------------------------------------------------
__global__ __launch_bounds__(64) void k_prep(const float* __restrict__ emb,
                                             ushort* __restrict__ Eb,
                                             float* __restrict__ rn) {
  int row = blockIdx.x, l = threadIdx.x;
  const float4* e4 = (const float4*)(emb + (size_t)row * DIM);
  float4 a = e4[2 * l], b = e4[2 * l + 1];
  float f[8] = {a.x, a.y, a.z, a.w, b.x, b.y, b.z, b.w};
  float s = 0.f;
#pragma unroll
  for (int q = 0; q < 8; q++) s += f[q] * f[q];
#pragma unroll
  for (int m = 1; m < 64; m <<= 1) s += __shfl_xor(s, m);
  if (l == 0) rn[row] = 1.0f / fmaxf(sqrtf(s), 1e-12f);
  union { short8 v; ushort u[8]; } o;
#pragma unroll
  for (int q = 0; q < 8; q++) o.u[q] = f2bf(f[q]);
  *(short8*)(Eb + (size_t)row * DIM + l * 8) = o.v;
}

// ---------------------------------------------------------------------------
// X init: bf16 X^T in both ping-pong buffers + exact fp32 unlabeled X
// ---------------------------------------------------------------------------
__global__ __launch_bounds__(256) void k_initX(ushort* __restrict__ X0,
                                               ushort* __restrict__ X1,
                                               float* __restrict__ Xu,
                                               const int* __restrict__ labels) {
  int j = blockIdx.x * 256 + threadIdx.x;       // 0..8191
  int c = blockIdx.y;                            // 0..111
  float v;
  if (j < NLAB) v = (labels[j] == c) ? 1.0f : 0.0f;
  else          v = (c < CREAL) ? 0.01f : 0.0f;
  ushort b = f2bf(v);
  X0[(size_t)c * BROWS + j] = b;
  X1[(size_t)c * BROWS + j] = b;
  if (j >= NLAB) Xu[(size_t)(j - NLAB) * CPAD + c] = (c < CREAL) ? 0.01f : 0.0f;
}

// ---------------------------------------------------------------------------
// MLP 512->256->128->64->1 (verified)
// ---------------------------------------------------------------------------
__global__ __launch_bounds__(256) void k_mlp(const float* __restrict__ emb,
                                             const float* __restrict__ W1, const float* __restrict__ b1,
                                             const float* __restrict__ W2, const float* __restrict__ b2,
                                             const float* __restrict__ W3, const float* __restrict__ b3,
                                             const float* __restrict__ Wc, const float* __restrict__ bc,
                                             float* __restrict__ out) {
  __shared__ float xs[4][512];
  __shared__ float h1[4][256];
  __shared__ float h2[4][128];
  __shared__ float h3[4][64];
  int t = threadIdx.x;
  int r0 = blockIdx.x * 4;
  {
    const float4* src = (const float4*)(emb + (size_t)r0 * DIM);
    float4* dst = (float4*)&xs[0][0];
    dst[t] = src[t];
    dst[t + 256] = src[t + 256];
  }
  __syncthreads();
  {
    float a0 = 0.f, a1 = 0.f, a2 = 0.f, a3 = 0.f;
    for (int k = 0; k < 512; k++) {
      float w = W1[k * 256 + t];
      a0 = fmaf(xs[0][k], w, a0);
      a1 = fmaf(xs[1][k], w, a1);
      a2 = fmaf(xs[2][k], w, a2);
      a3 = fmaf(xs[3][k], w, a3);
    }
    float bb = b1[t];
    h1[0][t] = fmaxf(a0 + bb, 0.f);
    h1[1][t] = fmaxf(a1 + bb, 0.f);
    h1[2][t] = fmaxf(a2 + bb, 0.f);
    h1[3][t] = fmaxf(a3 + bb, 0.f);
  }
  __syncthreads();
  {
    int c = t & 127, rb = (t >> 7) * 2;
    float a0 = 0.f, a1 = 0.f;
    for (int k = 0; k < 256; k++) {
      float w = W2[k * 128 + c];
      a0 = fmaf(h1[rb][k], w, a0);
      a1 = fmaf(h1[rb + 1][k], w, a1);
    }
    float bb = b2[c];
    h2[rb][c] = fmaxf(a0 + bb, 0.f);
    h2[rb + 1][c] = fmaxf(a1 + bb, 0.f);
  }
  __syncthreads();
  {
    int c = t & 63, r = t >> 6;
    float a = 0.f;
    for (int k = 0; k < 128; k++) a = fmaf(h2[r][k], W3[k * 64 + c], a);
    h3[r][c] = fmaxf(a + b3[c], 0.f);
  }
  __syncthreads();
  {
    int r = t >> 6, l = t & 63;
    float v = h3[r][l] * Wc[l];
#pragma unroll
    for (int m = 32; m; m >>= 1) v += __shfl_down(v, m);
    if (l == 0) out[r0 + r] = v + bc[0];
  }
}

// ---------------------------------------------------------------------------
// Similarity, single-bf16 MFMA, symmetry-reduced grid, single-buffer LDS
// staging (r6/r9 version verbatim — proven 93-95 us; dbuf regressed r11,
// no-LDS regressed r8).
// ---------------------------------------------------------------------------
__global__ __launch_bounds__(256) void k_simM(const ushort* __restrict__ Eb,
                                              const float* __restrict__ rn,
                                              ushort* __restrict__ S,
                                              double* __restrict__ meansum) {
  int x = blockIdx.x, y = blockIdx.y;
  if (x < 32 && y > x) return;
  __shared__ ushort Ei[128 * 40];
  __shared__ ushort Ej[128 * 40];
  __shared__ float redbuf[4];

  int t = threadIdx.x;
  int w = t >> 6, lane = t & 63;
  int m = lane & 15, g = lane >> 4;
  int ib = (w >> 1) * 64, jb = (w & 1) * 64;
  int i0 = x * 128, j0 = y * 128;

  floatx4 acc[4][4];
#pragma unroll
  for (int a = 0; a < 4; a++)
#pragma unroll
    for (int b = 0; b < 4; b++) acc[a][b] = (floatx4)0.0f;

  int lrow = t >> 1, lhalf = (t & 1) * 16;
  for (int kt = 0; kt < DIM; kt += 32) {
    __syncthreads();
    {
      const ushort* gi = Eb + (size_t)(i0 + lrow) * DIM + kt + lhalf;
      const ushort* gj = Eb + (size_t)(j0 + lrow) * DIM + kt + lhalf;
      int o = lrow * 40 + lhalf;
      *(short8*)&Ei[o]     = *(const short8*)gi;
      *(short8*)&Ei[o + 8] = *(const short8*)(gi + 8);
      *(short8*)&Ej[o]     = *(const short8*)gj;
      *(short8*)&Ej[o + 8] = *(const short8*)(gj + 8);
    }
    __syncthreads();

    short8 ah[4], bh[4];
#pragma unroll
    for (int rt = 0; rt < 4; rt++) ah[rt] = *(const short8*)&Ei[(ib + rt * 16 + m) * 40 + g * 8];
#pragma unroll
    for (int ct = 0; ct < 4; ct++) bh[ct] = *(const short8*)&Ej[(jb + ct * 16 + m) * 40 + g * 8];
#pragma unroll
    for (int rt = 0; rt < 4; rt++)
#pragma unroll
      for (int ct = 0; ct < 4; ct++)
        acc[rt][ct] = __builtin_amdgcn_mfma_f32_16x16x32_bf16(ah[rt], bh[ct], acc[rt][ct], 0, 0, 0);
  }

  bool dostore = (x >= 32);
  bool isdiag  = (x == y);
  float weight = (x < 32) ? (isdiag ? 1.0f : 2.0f) : ((y < 32) ? 2.0f : 1.0f);
  float lsum = 0.f;
#pragma unroll
  for (int rt = 0; rt < 4; rt++) {
    int gi0 = i0 + ib + rt * 16 + g * 4;
    float4 rni = *(const float4*)(rn + gi0);
#pragma unroll
    for (int ct = 0; ct < 4; ct++) {
      int gj = j0 + jb + ct * 16 + m;
      float rnj = rn[gj];
#pragma unroll
      for (int r = 0; r < 4; r++) {
        int gi = gi0 + r;
        float rv = (r == 0) ? rni.x : (r == 1) ? rni.y : (r == 2) ? rni.z : rni.w;
        float s = acc[rt][ct][r] * rv * rnj;
        if (isdiag && gi == gj) s = 0.f;
        s = fminf(fmaxf(s, 0.f), 1.f);
        lsum += s;
        if (dostore) S[(size_t)(gi - NLAB) * BROWS + gj] = f2bf(s);
      }
    }
  }
  lsum *= weight;
#pragma unroll
  for (int d = 1; d < 64; d <<= 1) lsum += __shfl_xor(lsum, d);
  if (lane == 0) redbuf[w] = lsum;
  __syncthreads();
  if (t == 0) atomicAdd(meansum, (double)(redbuf[0] + redbuf[1] + redbuf[2] + redbuf[3]));
}

// ---------------------------------------------------------------------------
// One replicator iteration (r6 structure, 256 blocks x 1024 thr).  Plain
// (LLC-served) loads for S/Au (r11).  NEW: (1) Plab/Xu prefetched into
// registers at kernel entry — their latency is hidden behind the GEMM phase
// instead of exposed naked between reduction barriers; (2) X^T write-back
// staged through an LDS transpose buffer (aliased on the dead `part`
// region) and written as coalesced ushort2 runs — 16x fewer write txns
// than the old per-lane 2B scatter.  Values byte-identical.
// Convergence: skip iff errsq[it-1] <= TOL^2 (skip chains = reference loop).
// ---------------------------------------------------------------------------
__global__ __launch_bounds__(1024, 4) void k_iter(const ushort* __restrict__ S,
                                                  ushort* __restrict__ Au,
                                                  const ushort* __restrict__ XTr,
                                                  ushort* __restrict__ XTw,
                                                  float* __restrict__ Xu,
                                                  float* __restrict__ Plab,
                                                  float* __restrict__ hist,
                                                  float* __restrict__ errsq,
                                                  const double* __restrict__ ms,
                                                  int it) {
  if (it > 0 && errsq[it - 1] <= 1e-6f) return;
  __shared__ float part[8][16 * 113];   // 57856 B (reused as xbuf after last read)
  __shared__ float Pbuf[16 * 114];      //  7296 B
  __shared__ float dsqbuf[16];
  ushort* xbuf = (ushort*)&part[0][0];  // [112][18] ushort transpose stage (4032 B)
  int t = threadIdx.x;
  int w = t >> 6, lane = t & 63;
  int m = lane & 15, g = lane >> 4;
  int r0 = blockIdx.x * 16;             // unlabeled row base (i' space)

  // ---- entry prefetches (latency hidden behind GEMM phase) ----
  float2 xo = make_float2(0.f, 0.f);
  if (lane < 56) xo = *(const float2*)(Xu + (size_t)(r0 + w) * CPAD + lane * 2);
  float pl_pre[2] = {0.f, 0.f};
  if (it > 0) {
#pragma unroll
    for (int q = 0; q < 2; q++) {
      int idx = t + q * 1024;
      if (idx < 16 * CPAD)
        pl_pre[q] = Plab[(size_t)(r0 + idx / CPAD) * CPAD + idx % CPAD];
    }
  }

  floatx4 acc[7];
#pragma unroll
  for (int c = 0; c < 7; c++) acc[c] = (floatx4)0.0f;

  if (it == 0) {
    float mean = (float)(ms[0] * (1.0 / ((double)BROWS * (double)BROWS)));
    int kw = w * 512;                   // wave w: k in [w*512, w*512+512)
    for (int ks = 0; ks < 16; ks++) {
      int kk = kw + ks * 32;
      size_t so = (size_t)(r0 + m) * BROWS + kk + g * 8;
      short8 a = *(const short8*)(S + so);
      union { short8 v; ushort u[8]; } ua; ua.v = a;
#pragma unroll
      for (int e = 0; e < 8; e++) {
        float s = bf2f(ua.u[e]);
        float av = (s < mean) ? 1.0f : 1.0f - s;
        ua.u[e] = f2bf(av);
      }
      a = ua.v;
      if (w >= 8)   // unlabeled K half -> persist for it>0
        *(short8*)(Au + (size_t)(r0 + m) * NUNL + (kk - NLAB) + g * 8) = a;
#pragma unroll
      for (int ct = 0; ct < 7; ct++) {
        short8 b = *(const short8*)(XTr + (size_t)(ct * 16 + m) * BROWS + kk + g * 8);
        acc[ct] = __builtin_amdgcn_mfma_f32_16x16x32_bf16(a, b, acc[ct], 0, 0, 0);
      }
    }
  } else {
    int kw = w * 256;                   // Au-relative: wave w k in [w*256,+256)
    size_t abase = (size_t)(r0 + m) * NUNL + kw + g * 8;
    size_t bbase = (size_t)m * BROWS + NLAB + kw + g * 8;
    for (int ks = 0; ks < 8; ks++) {
      short8 a = *(const short8*)(Au + abase + ks * 32);
#pragma unroll
      for (int ct = 0; ct < 7; ct++) {
        short8 b = *(const short8*)(XTr + bbase + (size_t)ct * 16 * BROWS + ks * 32);
        acc[ct] = __builtin_amdgcn_mfma_f32_16x16x32_bf16(a, b, acc[ct], 0, 0, 0);
      }
    }
  }

  // ---- two-phase reduction of 16 wave-partials through 8 LDS buffers ----
  // (D-frag map: row = g*4+r, col = ct*16+m)
  if (w < 8) {
#pragma unroll
    for (int ct = 0; ct < 7; ct++)
#pragma unroll
      for (int r = 0; r < 4; r++)
        part[w][(g * 4 + r) * 113 + ct * 16 + m] = acc[ct][r];
  }
  __syncthreads();
  float sA[2] = {0.f, 0.f}, sB[2] = {0.f, 0.f};
#pragma unroll
  for (int q = 0; q < 2; q++) {
    int idx = t + q * 1024;
    if (idx < 16 * CPAD) {
      int row = idx / CPAD, col = idx % CPAD;
      int o = row * 113 + col;
      sA[q] = ((part[0][o] + part[1][o]) + (part[2][o] + part[3][o]))
            + ((part[4][o] + part[5][o]) + (part[6][o] + part[7][o]));
    }
  }
  __syncthreads();
  if (w >= 8) {
#pragma unroll
    for (int ct = 0; ct < 7; ct++)
#pragma unroll
      for (int r = 0; r < 4; r++)
        part[w - 8][(g * 4 + r) * 113 + ct * 16 + m] = acc[ct][r];
  }
  __syncthreads();
#pragma unroll
  for (int q = 0; q < 2; q++) {
    int idx = t + q * 1024;
    if (idx < 16 * CPAD) {
      int row = idx / CPAD, col = idx % CPAD;
      int o = row * 113 + col;
      sB[q] = ((part[0][o] + part[1][o]) + (part[2][o] + part[3][o]))
            + ((part[4][o] + part[5][o]) + (part[6][o] + part[7][o]));
      float P;
      size_t go = (size_t)(r0 + row) * CPAD + col;
      if (it == 0) { Plab[go] = sA[q]; P = sA[q] + sB[q]; }  // waves 0-7 = labeled K
      else         { P = sA[q] + sB[q] + pl_pre[q]; }
      Pbuf[row * 114 + col] = P;
    }
  }
  __syncthreads();                      // part reads done -> xbuf may alias it

  // ---- fused epilogue: wave w handles row w ----
  int gr = r0 + w;
  bool act = lane < 56;
  float2 p = make_float2(0.f, 0.f);
  if (act) p = *(const float2*)&Pbuf[w * 114 + lane * 2];
  float2 xn;
  xn.x = xo.x * p.x;
  xn.y = xo.y * p.y;
  float s = xn.x + xn.y;
#pragma unroll
  for (int d = 1; d < 64; d <<= 1) s += __shfl_xor(s, d);
  float inv = 1.0f / s;
  float ent = 0.f, dsq = 0.f;
  if (act) {
    xn.x *= inv; xn.y *= inv;
    ent = -(xn.x * log2f(xn.x + 1e-20f) + xn.y * log2f(xn.y + 1e-20f));
    float dx = xn.x - xo.x, dy = xn.y - xo.y;
    dsq = dx * dx + dy * dy;
    *(float2*)(Xu + (size_t)gr * CPAD + lane * 2) = xn;
    int c0 = lane * 2;
    xbuf[c0 * 18 + w]       = f2bf(xn.x);   // [c][18] stride: 2-way max bank alias
    xbuf[(c0 + 1) * 18 + w] = f2bf(xn.y);
  }
#pragma unroll
  for (int d = 1; d < 64; d <<= 1) { ent += __shfl_xor(ent, d); dsq += __shfl_xor(dsq, d); }
  if (lane == 0) {
    hist[gr] += ent;
    dsqbuf[w] = dsq;
  }
  __syncthreads();

  // ---- coalesced X^T write-back: 8 threads x ushort2 = 32B run per column ----
  if (t < CPAD * 8) {
    int c = t >> 3, jl = (t & 7) * 2;
    ushort2 v = *(const ushort2*)&xbuf[c * 18 + jl];
    *(ushort2*)(XTw + (size_t)c * BROWS + NLAB + r0 + jl) = v;
  }
  if (t == 0) {
    float ds = 0.f;
#pragma unroll
    for (int i = 0; i < 16; i++) ds += dsqbuf[i];
    atomicAdd(&errsq[it], ds);
  }
}

__global__ __launch_bounds__(256) void k_final(const float* __restrict__ hist,
                                               float* __restrict__ out) {
  int i = blockIdx.x * 256 + threadIdx.x;
  float yt = (i < NLAB) ? 0.0f : hist[i - NLAB] * (1.0f / 30.0f);
  out[BROWS + i] = yt;
  out[2 * BROWS + i] = (i < NLAB) ? 1.0f : 0.0f;
}

// ---------------------------------------------------------------------------
extern "C" void kernel_launch(void* const* d_in, const int* in_sizes, int n_in,
                              void* d_out, int out_size, void* d_ws, size_t ws_size,
                              hipStream_t stream) {
  const float* emb    = (const float*)d_in[1];
  const int*   labels = (const int*)d_in[2];
  const float* W1 = (const float*)d_in[3];
  const float* b1 = (const float*)d_in[4];
  const float* W2 = (const float*)d_in[5];
  const float* b2 = (const float*)d_in[6];
  const float* W3 = (const float*)d_in[7];
  const float* b3 = (const float*)d_in[8];
  const float* Wc = (const float*)d_in[9];
  const float* bc = (const float*)d_in[10];
  float* out = (float*)d_out;

  char* ws = (char*)d_ws;
  ushort* S    = (ushort*)(ws + OFF_S);
  ushort* Au   = (ushort*)(ws + OFF_AU);
  ushort* Eb   = (ushort*)(ws + OFF_EB);
  ushort* XT0  = (ushort*)(ws + OFF_XT0);
  ushort* XT1  = (ushort*)(ws + OFF_XT1);
  float*  Xu   = (float*)(ws + OFF_XU);
  float*  Plab = (float*)(ws + OFF_PL);
  float*  hist = (float*)(ws + OFF_HIST);
  float*  errs = (float*)(ws + OFF_ERR);
  double* ms   = (double*)(ws + OFF_MS);
  float*  rn   = (float*)(ws + OFF_RN);

  // zero hist + errsq + mean accumulator
  hipMemsetAsync(ws + OFF_HIST, 0, MEMSET_LEN, stream);

  k_prep<<<BROWS, 64, 0, stream>>>(emb, Eb, rn);
  k_mlp<<<BROWS / 4, 256, 0, stream>>>(emb, W1, b1, W2, b2, W3, b3, Wc, bc, out);

  { dim3 g(BROWS / 128, BROWS / 128); k_simM<<<g, 256, 0, stream>>>(Eb, rn, S, ms); }

  // overlay init (Eb dead now)
  { dim3 g(BROWS / 256, CPAD); k_initX<<<g, 256, 0, stream>>>(XT0, XT1, Xu, labels); }

  for (int it = 0; it < MAXIT; it++) {
    const ushort* XTr = (it & 1) ? XT1 : XT0;
    ushort*       XTw = (it & 1) ? XT0 : XT1;
    k_iter<<<NUNL / 16, 1024, 0, stream>>>(S, Au, XTr, XTw, Xu, Plab, hist, errs, ms, it);
  }

  k_final<<<BROWS / 256, 256, 0, stream>>>(hist, out);
}